// Round 10
// baseline (227.984 us; speedup 1.0000x reference)
//
#include <hip/hip_runtime.h>
#include <hip/hip_bf16.h>
#include <math.h>

// Problem constants
#define NB 65536
#define ND 256
#define NE 16
#define NH 64
#define NA 18

typedef __bf16 bf16;
typedef __bf16 bf16x4 __attribute__((ext_vector_type(4)));
typedef __bf16 bf16x8 __attribute__((ext_vector_type(8)));
typedef float  f32x4  __attribute__((ext_vector_type(4)));

// ---- workspace layout (bytes) ----
#define OFF_WCAT 0u
#define OFF_BCAT 1048576u
#define OFF_PW1  1052672u
#define OFF_B1   2101248u
#define OFF_CUR  2109440u
#define OFF_PERM 2109504u

__device__ __forceinline__ float rcp_(float x) { return __builtin_amdgcn_rcpf(x); }
__device__ __forceinline__ float sigm_(float x) { return rcp_(1.f + __expf(-x)); }
__device__ __forceinline__ float tanh_(float x) {
    float cl = fminf(fmaxf(x, -15.f), 15.f);
    float e = __expf(2.f * cl);
    return (e - 1.f) * rcp_(e + 1.f);
}

__device__ __forceinline__ void gl2lds16(const void* g, void* l) {
    __builtin_amdgcn_global_load_lds(
        (const __attribute__((address_space(1))) unsigned int*)g,
        (__attribute__((address_space(3))) unsigned int*)l, 16, 0, 0);
}

// ---------------- prep1: pack LSTM weights into DMA/frag order (unchanged; 0-conflict) ----------------
__global__ void k_prep1(const float* __restrict__ W_ih, const float* __restrict__ W_hh,
                        const float* __restrict__ b_ih, const float* __restrict__ b_hh,
                        char* __restrict__ ws) {
    int t = blockIdx.x * 256 + threadIdx.x;        // 65536 units
    int kstep = t >> 13;
    int cb    = (t >> 11) & 3;
    int idx   = t & 2047;
    int kf = idx >> 10, g = (idx >> 8) & 3, lk = (idx >> 6) & 3, u = idx & 63;
    int col = g * 256 + cb * 64 + (u ^ lk);
    int k0  = kstep * 64 + (kf * 4 + lk) * 8;
    const float* src = (k0 < 256) ? (W_ih + (size_t)col * 256 + k0)
                                  : (W_hh + (size_t)col * 256 + (k0 - 256));
    float4 v0 = *(const float4*)(src);
    float4 v1 = *(const float4*)(src + 4);
    bf16x8 o;
    o[0] = (bf16)v0.x; o[1] = (bf16)v0.y; o[2] = (bf16)v0.z; o[3] = (bf16)v0.w;
    o[4] = (bf16)v1.x; o[5] = (bf16)v1.y; o[6] = (bf16)v1.z; o[7] = (bf16)v1.w;
    *(bf16x8*)((bf16*)(ws + OFF_WCAT) + (size_t)t * 8) = o;
    if (t < 1024) ((float*)(ws + OFF_BCAT))[t] = b_ih[t] + b_hh[t];
    if (t < 16)   ((int*)(ws + OFF_CUR))[t] = t * 65536;
}

// ---------------- prep2: pack expert layer-1 weights ----------------
__global__ void k_prep2(const float* __restrict__ Wa1, const float* __restrict__ Wc1,
                        const float* __restrict__ ba1, const float* __restrict__ bc1,
                        char* __restrict__ ws) {
    int t = blockIdx.x * 256 + threadIdx.x;
    bf16* PW1 = (bf16*)(ws + OFF_PW1);
    int col = t & 127, kc = (t >> 7) & 31, e = t >> 12;
    bf16x8 o;
#pragma unroll
    for (int j = 0; j < 8; ++j) {
        int k = kc * 8 + j;
        float v = (col < 64) ? Wa1[((size_t)e * 256 + k) * 64 + col]
                             : Wc1[((size_t)e * 256 + k) * 64 + (col - 64)];
        o[j] = (bf16)v;
    }
    *(bf16x8*)(PW1 + (((size_t)e * 32 + kc) * 128 + col) * 8) = o;
    if (t < 2048) {
        int e2 = t >> 7, c = t & 127;
        ((float*)(ws + OFF_B1))[t] = (c < 64) ? ba1[e2 * 64 + c] : bc1[e2 * 64 + (c - 64)];
    }
}

// ---------------- scatter ----------------
__global__ void k_scatter(const int* __restrict__ idxs, char* __restrict__ ws) {
    __shared__ int lh[16], lbase[16];
    int t = threadIdx.x;
    int i = blockIdx.x * 256 + t;
    if (t < 16) lh[t] = 0;
    __syncthreads();
    int e = idxs[i];
    int r = atomicAdd(&lh[e], 1);
    __syncthreads();
    int* cur = (int*)(ws + OFF_CUR);
    if (t < 16) lbase[t] = atomicAdd(&cur[t], lh[t]);
    __syncthreads();
    ((int*)(ws + OFF_PERM))[lbase[e] + r] = i;
}

// ---------------- k_lstm v10: 128-row tile (2x work/window), SAFE drain sync ----------------
// 256 thr (4 waves); tile = 128 rows x 64 c-cols (x4 gates), BK=64, 8 K-steps.
// Wave w owns c-cols [cb*64+16w, +16), all 128 rows: acc[8 m][4 g] = 128 AGPR.
// Per step: hoist 8 B-frags->regs; __syncthreads; DMA B(t+1) into same buffer +
// ds_write A(t+1) + issue A(t+2) loads; 64 MFMA; __syncthreads (full drain = safe).
// Epilogue: cin/cn/hn bounced through swizzled LDS -> fully coalesced float4 I/O.
__global__ __launch_bounds__(256, 2) void k_lstm(
    const float* __restrict__ obs, const float* __restrict__ hin,
    const float* __restrict__ cin, const float* __restrict__ bcat,
    const char* __restrict__ wcat,
    float* __restrict__ hout, float* __restrict__ cout) {
    __shared__ alignas(16) char Abuf[2][16384];   // [kc 8][row 128][16B], XOR-swizzled
    __shared__ alignas(16) char Bbuf[32768];      // single buffer, DMA frag-order
    const int tid  = threadIdx.x;
    const int w = tid >> 6, lane = tid & 63;
    const int lr = lane & 15, lk = lane >> 4;
    const int bid = blockIdx.x;
    const int xcd = bid & 7;
    const int cb  = (bid >> 3) & 3;
    const int rb  = ((bid >> 5) << 3) | xcd;      // 0..511 (XCD-grouped panel sharers)
    const int row0 = rb * 128;
    const int colc = cb * 64 + w * 16 + lr;
    const int srw = tid >> 1, sf = tid & 1;       // A-stager: row srw, k-half sf

    const char* WcatBlk = wcat + (size_t)cb * 32768;   // + kstep*131072
    const float* baseO0 = obs + (size_t)(row0 + srw) * 256 + sf * 32;
    const float* baseH0 = hin + (size_t)(row0 + srw) * 256 + sf * 32;

    int offE[8], offO[8];
#pragma unroll
    for (int m = 0; m < 8; ++m) {
        int R = m * 16 + lr;
        offE[m] = lk * 2048 + ((R ^ lk) * 16);
        offO[m] = (lk + 4) * 2048 + ((R ^ (lk + 4)) * 16);
    }
    const int bBase = lk * 1024 + (((w * 16 + lr) ^ lk) * 16);

    f32x4 acc[8][4];
#pragma unroll
    for (int m = 0; m < 8; ++m)
#pragma unroll
        for (int g = 0; g < 4; ++g)
#pragma unroll
            for (int r = 0; r < 4; ++r) acc[m][g][r] = 0.f;

#define STAGE_B(ks)                                                          \
    {                                                                        \
        const char* srcB_ = WcatBlk + (size_t)(ks) * 131072;                 \
        _Pragma("unroll")                                                    \
        for (int i_ = 0; i_ < 8; ++i_) {                                     \
            int so_ = (w * 8 + i_) * 1024;                                   \
            gl2lds16(srcB_ + so_ + lane * 16, &Bbuf[so_]);                   \
        }                                                                    \
    }
#define LOAD_A(ks)                                                           \
    {                                                                        \
        const float* s0_ = ((ks) < 4) ? (baseO0 + (ks) * 64)                 \
                                      : (baseH0 + ((ks) - 4) * 64);          \
        pf0 = *(const float4*)(s0_);      pf1 = *(const float4*)(s0_ + 4);   \
        pf2 = *(const float4*)(s0_ + 8);  pf3 = *(const float4*)(s0_ + 12);  \
        pf4 = *(const float4*)(s0_ + 16); pf5 = *(const float4*)(s0_ + 20);  \
        pf6 = *(const float4*)(s0_ + 24); pf7 = *(const float4*)(s0_ + 28);  \
    }
#define CVW(bi, q, va, vb)                                                   \
    {                                                                        \
        int kc_ = sf * 4 + (q);                                              \
        bf16x8 o_;                                                           \
        o_[0] = (bf16)va.x; o_[1] = (bf16)va.y; o_[2] = (bf16)va.z;          \
        o_[3] = (bf16)va.w; o_[4] = (bf16)vb.x; o_[5] = (bf16)vb.y;          \
        o_[6] = (bf16)vb.z; o_[7] = (bf16)vb.w;                              \
        *(bf16x8*)(&Abuf[bi][kc_ * 2048 + ((srw ^ kc_) * 16)]) = o_;         \
    }
#define WRITE_A(bi)                                                          \
    { CVW(bi, 0, pf0, pf1); CVW(bi, 1, pf2, pf3);                            \
      CVW(bi, 2, pf4, pf5); CVW(bi, 3, pf6, pf7); }
#define MFMA_HALF(cur, offA, q0, q1, q2, q3)                                 \
    {                                                                        \
        const char* Ab_ = Abuf[cur];                                         \
        _Pragma("unroll")                                                    \
        for (int m = 0; m < 8; ++m) {                                        \
            bf16x8 a_ = *(const bf16x8*)(Ab_ + offA[m]);                     \
            acc[m][0] = __builtin_amdgcn_mfma_f32_16x16x32_bf16(a_, q0, acc[m][0], 0, 0, 0); \
            acc[m][1] = __builtin_amdgcn_mfma_f32_16x16x32_bf16(a_, q1, acc[m][1], 0, 0, 0); \
            acc[m][2] = __builtin_amdgcn_mfma_f32_16x16x32_bf16(a_, q2, acc[m][2], 0, 0, 0); \
            acc[m][3] = __builtin_amdgcn_mfma_f32_16x16x32_bf16(a_, q3, acc[m][3], 0, 0, 0); \
        }                                                                    \
    }
    // One step. Entering: Bbuf = B(T) complete, Abuf[T&1] = A(T), pf = A(T+1).
#define PIPE_STEP(T)                                                         \
    {                                                                        \
        const int CUR = (T) & 1;                                             \
        const char* Bb0 = Bbuf + bBase;                                      \
        bf16x8 br0 = *(const bf16x8*)(Bb0);                                  \
        bf16x8 br1 = *(const bf16x8*)(Bb0 + 4096);                           \
        bf16x8 br2 = *(const bf16x8*)(Bb0 + 8192);                           \
        bf16x8 br3 = *(const bf16x8*)(Bb0 + 12288);                          \
        bf16x8 br4 = *(const bf16x8*)(Bb0 + 16384);                          \
        bf16x8 br5 = *(const bf16x8*)(Bb0 + 20480);                          \
        bf16x8 br6 = *(const bf16x8*)(Bb0 + 24576);                          \
        bf16x8 br7 = *(const bf16x8*)(Bb0 + 28672);                          \
        __syncthreads();                         /* all B(T) reads done */   \
        if ((T) < 7) {                                                       \
            STAGE_B((T) + 1);                    /* DMA into freed Bbuf */   \
            WRITE_A(CUR ^ 1);                    /* A(T+1) from pf regs */   \
        }                                                                    \
        if ((T) < 6) LOAD_A((T) + 2);                                        \
        if ((T) == 6) {                          /* coalesced cin prefetch */ \
            const float* cs_ = cin + (size_t)(row0 + srw) * 256 + cb * 64 + sf * 32; \
            ci0 = *(const float4*)(cs_);      ci1 = *(const float4*)(cs_ + 4);  \
            ci2 = *(const float4*)(cs_ + 8);  ci3 = *(const float4*)(cs_ + 12); \
            ci4 = *(const float4*)(cs_ + 16); ci5 = *(const float4*)(cs_ + 20); \
            ci6 = *(const float4*)(cs_ + 24); ci7 = *(const float4*)(cs_ + 28); \
        }                                                                    \
        MFMA_HALF(CUR, offE, br0, br1, br2, br3);                            \
        MFMA_HALF(CUR, offO, br4, br5, br6, br7);                            \
        __syncthreads();                         /* full drain: B(T+1)+A safe */ \
    }

    float4 pf0, pf1, pf2, pf3, pf4, pf5, pf6, pf7;   // A prefetch (1-deep)
    float4 ci0, ci1, ci2, ci3, ci4, ci5, ci6, ci7;   // cin (loaded T=6)

    // ---- prologue ----
    LOAD_A(0);
    STAGE_B(0);
    WRITE_A(0);                 // compiler-inserted wait for A(0) regs
    LOAD_A(1);
    __syncthreads();            // drain: B(0) landed, A(0) writes visible

    PIPE_STEP(0); PIPE_STEP(1); PIPE_STEP(2); PIPE_STEP(3);
    PIPE_STEP(4); PIPE_STEP(5); PIPE_STEP(6); PIPE_STEP(7);

#undef STAGE_B
#undef LOAD_A
#undef CVW
#undef WRITE_A
#undef MFMA_HALF
#undef PIPE_STEP

    // ---- epilogue: swizzled-LDS bounce, fully coalesced I/O ----
    // fp32 [128 rows][16 slots of 16B]: byte = row*256 + ((s ^ (row&15))*16)
#define EPI(row, s) ((row) * 256 + ((((s) ^ ((row) & 15))) * 16))
    char* CNbuf = (char*)Abuf;        // 32 KB (A buffers now free)
    // 1) cin regs -> LDS (Bbuf), coalesced-write side
    *(float4*)(&Bbuf[EPI(srw, sf * 8 + 0)]) = ci0;
    *(float4*)(&Bbuf[EPI(srw, sf * 8 + 1)]) = ci1;
    *(float4*)(&Bbuf[EPI(srw, sf * 8 + 2)]) = ci2;
    *(float4*)(&Bbuf[EPI(srw, sf * 8 + 3)]) = ci3;
    *(float4*)(&Bbuf[EPI(srw, sf * 8 + 4)]) = ci4;
    *(float4*)(&Bbuf[EPI(srw, sf * 8 + 5)]) = ci5;
    *(float4*)(&Bbuf[EPI(srw, sf * 8 + 6)]) = ci6;
    *(float4*)(&Bbuf[EPI(srw, sf * 8 + 7)]) = ci7;
    __syncthreads();

    // 2) per-point: read cin, LSTM pointwise, cn->CNbuf, hn->Bbuf (sole owner)
    {
        float bi = bcat[colc], bf_ = bcat[256 + colc], bg = bcat[512 + colc], bo = bcat[768 + colc];
        const int cwi = w * 16 + lr;              // col within 64
        const int s_  = cwi >> 2, word_ = (cwi & 3) * 4;
#pragma unroll
        for (int m = 0; m < 8; ++m) {
#pragma unroll
            for (int r = 0; r < 4; ++r) {
                int rl = m * 16 + lk * 4 + r;     // row within 128
                int ea = EPI(rl, s_) + word_;
                float co = *(const float*)(&Bbuf[ea]);
                float gi = acc[m][0][r] + bi;
                float gf = acc[m][1][r] + bf_;
                float gg = acc[m][2][r] + bg;
                float go = acc[m][3][r] + bo;
                float iv = sigm_(gi), fv = sigm_(gf), gv = tanh_(gg), ov = sigm_(go);
                float cn = fv * co + iv * gv;
                float hn = ov * tanh_(cn);
                *(float*)(&CNbuf[ea]) = cn;
                *(float*)(&Bbuf[ea])  = hn;       // in-place: same sole owner
            }
        }
    }
    __syncthreads();

    // 3) coalesced float4 stores
    {
        float* cO = cout + (size_t)(row0 + srw) * 256 + cb * 64 + sf * 32;
        float* hO = hout + (size_t)(row0 + srw) * 256 + cb * 64 + sf * 32;
#pragma unroll
        for (int j = 0; j < 8; ++j) {
            float4 vc = *(const float4*)(&CNbuf[EPI(srw, sf * 8 + j)]);
            *(float4*)(cO + j * 4) = vc;
        }
#pragma unroll
        for (int j = 0; j < 8; ++j) {
            float4 vh = *(const float4*)(&Bbuf[EPI(srw, sf * 8 + j)]);
            *(float4*)(hO + j * 4) = vh;
        }
    }
#undef EPI
}

// ---------------- k_expert: per-(expert, 64-row chunk) routed MLPs ----------------
__global__ __launch_bounds__(256) void k_expert(
    const float* __restrict__ Wa2, const float* __restrict__ ba2,
    const float* __restrict__ Wc2, const float* __restrict__ bc2,
    char* __restrict__ ws, const float* __restrict__ hsrc,
    float* __restrict__ lout, float* __restrict__ vout) {
    const int e = blockIdx.y;
    const int* cur = (const int*)(ws + OFF_CUR);
    int cnt = cur[e] - e * 65536;
    int r0 = blockIdx.x * 64;
    if (r0 >= cnt) return;
    int nr = min(64, cnt - r0);
    const int* permE = (const int*)(ws + OFF_PERM) + (size_t)e * 65536 + r0;

    __shared__ int rows_s[64];
    __shared__ alignas(16) char smem[128 * 66 * 4];
    bf16*  Alds = (bf16*)smem;
    float* haF  = (float*)smem;

    int t = threadIdx.x;
    if (t < 64) rows_s[t] = permE[(t < nr) ? t : 0];
    __syncthreads();

    {
        int rowi = t >> 2, q = t & 3;
        const float* hp = hsrc + (size_t)rows_s[rowi] * 256;
#pragma unroll
        for (int s = 0; s < 8; ++s) {
            int kc = s * 4 + q;
            float4 v0 = *(const float4*)(hp + kc * 8);
            float4 v1 = *(const float4*)(hp + kc * 8 + 4);
            bf16x8 o;
            o[0] = (bf16)v0.x; o[1] = (bf16)v0.y; o[2] = (bf16)v0.z; o[3] = (bf16)v0.w;
            o[4] = (bf16)v1.x; o[5] = (bf16)v1.y; o[6] = (bf16)v1.z; o[7] = (bf16)v1.w;
            *(bf16x8*)(Alds + ((size_t)kc * 64 + rowi) * 8) = o;
        }
    }
    __syncthreads();

    const bf16* PW1 = (const bf16*)(ws + OFF_PW1) + (size_t)e * 32 * 128 * 8;
    const float* b1 = (const float*)(ws + OFF_B1) + e * 128;
    int wave = t >> 6, lane = t & 63, lr = lane & 15, lk = lane >> 4;

    f32x4 acc[4][2];
#pragma unroll
    for (int m = 0; m < 4; ++m)
#pragma unroll
        for (int n = 0; n < 2; ++n)
#pragma unroll
            for (int r = 0; r < 4; ++r) acc[m][n][r] = 0.f;

#pragma unroll
    for (int kf = 0; kf < 8; ++kf) {
        bf16x8 a[4], bb[2];
#pragma unroll
        for (int m = 0; m < 4; ++m)
            a[m] = *(const bf16x8*)(Alds + (((kf * 4 + lk) * 64) + (m * 16 + lr)) * 8);
#pragma unroll
        for (int n = 0; n < 2; ++n) {
            int colh = wave * 32 + n * 16 + lr;
            int kc = kf * 4 + lk;
            bb[n] = *(const bf16x8*)(PW1 + ((size_t)kc * 128 + colh) * 8);
        }
#pragma unroll
        for (int m = 0; m < 4; ++m)
#pragma unroll
            for (int n = 0; n < 2; ++n)
                acc[m][n] = __builtin_amdgcn_mfma_f32_16x16x32_bf16(a[m], bb[n], acc[m][n], 0, 0, 0);
    }
    __syncthreads();

#pragma unroll
    for (int m = 0; m < 4; ++m)
#pragma unroll
        for (int n = 0; n < 2; ++n) {
            int colh = wave * 32 + n * 16 + lr;
            float bbv = b1[colh];
#pragma unroll
            for (int r = 0; r < 4; ++r) {
                int row = m * 16 + lk * 4 + r;
                haF[colh * 66 + row] = tanh_(acc[m][n][r] + bbv);
            }
        }
    __syncthreads();

    int row = t & 63;
    int grow = rows_s[row];
    bool valid = row < nr;
#pragma unroll
    for (int p = 0; p < 5; ++p) {
        int aI = p * 4 + (t >> 6);
        if (aI < NA) {
            float s = ba2[e * NA + aI];
            for (int hh = 0; hh < 64; ++hh)
                s += haF[hh * 66 + row] * Wa2[((size_t)e * 64 + hh) * NA + aI];
            if (valid) lout[(size_t)grow * NA + aI] = s;
        }
    }
    if (t < 64) {
        float s = bc2[e];
        for (int hh = 0; hh < 64; ++hh)
            s += haF[(64 + hh) * 66 + row] * Wc2[e * 64 + hh];
        if (valid) vout[grow] = s;
    }
}

extern "C" void kernel_launch(void* const* d_in, const int* in_sizes, int n_in,
                              void* d_out, int out_size, void* d_ws, size_t ws_size,
                              hipStream_t stream) {
    const float* obs  = (const float*)d_in[0];
    const float* h    = (const float*)d_in[1];
    const float* c    = (const float*)d_in[2];
    const int*   idxs = (const int*)d_in[3];
    const float* W_ih = (const float*)d_in[4];
    const float* W_hh = (const float*)d_in[5];
    const float* b_ih = (const float*)d_in[6];
    const float* b_hh = (const float*)d_in[7];
    const float* Wa1  = (const float*)d_in[8];
    const float* ba1  = (const float*)d_in[9];
    const float* Wa2  = (const float*)d_in[10];
    const float* ba2  = (const float*)d_in[11];
    const float* Wc1  = (const float*)d_in[12];
    const float* bc1  = (const float*)d_in[13];
    const float* Wc2  = (const float*)d_in[14];
    const float* bc2  = (const float*)d_in[15];

    float* out  = (float*)d_out;
    float* hout = out;
    float* cout = out + (size_t)NB * ND;
    float* lout = out + (size_t)2 * NB * ND;
    float* vout = lout + (size_t)NB * NA;
    char* ws = (char*)d_ws;

    k_prep1<<<dim3(256), dim3(256), 0, stream>>>(W_ih, W_hh, b_ih, b_hh, ws);
    k_prep2<<<dim3(256), dim3(256), 0, stream>>>(Wa1, Wc1, ba1, bc1, ws);
    k_scatter<<<dim3(256), dim3(256), 0, stream>>>(idxs, ws);
    k_lstm<<<dim3(2048), dim3(256), 0, stream>>>(
        obs, h, c, (const float*)(ws + OFF_BCAT), (const char*)(ws + OFF_WCAT), hout, cout);
    k_expert<<<dim3(1024, 16), dim3(256), 0, stream>>>(
        Wa2, ba2, Wc2, bc2, ws, hout, lout, vout);
}